// Round 5
// baseline (146.626 us; speedup 1.0000x reference)
//
#include <hip/hip_runtime.h>
#include <stdint.h>

#define B_    4096
#define T_    48
#define D_    35
#define H_    64
#define KROW  160           // A-row stride (elems) = MFMA K extent (5*32)
#define BT    8             // real batch rows per block (rows 8..15 of tile are zero)
#define ROWEL (T_ * D_)     // 1680
#define L2E   1.44269504f

typedef float f32x4 __attribute__((ext_vector_type(4)));
typedef short bf16x8 __attribute__((ext_vector_type(8)));

__device__ __forceinline__ uint32_t fbits(float x) { union { float f; uint32_t u; } v; v.f = x; return v.u; }
__device__ __forceinline__ float bitsf(uint32_t u) { union { uint32_t u; float f; } v; v.u = u; return v.f; }
__device__ __forceinline__ float bf2f(unsigned short b) { return bitsf(((uint32_t)b) << 16); }
__device__ __forceinline__ unsigned short f2bf_rne(float x) {
    uint32_t u = fbits(x);
    return (unsigned short)((u + 0x7fffu + ((u >> 16) & 1u)) >> 16);
}
__device__ __forceinline__ float rcp_(float x) { return __builtin_amdgcn_rcpf(x); }
__device__ __forceinline__ float exp2_(float x) { return __builtin_amdgcn_exp2f(x); }

// K-axis layout (A tiles and weight fragments):
//   k 0..34 = x_c -> W_ih[:,0:35] ; k 35..69 = m -> W_ih[:,35:70]
//   k 70..71 = 0  ; k 72..135 = h -> W_hh    ; k 136..159 = 0

__global__ __launch_bounds__(256, 2)
void brits_main(const float* __restrict__ x_t, const float* __restrict__ masks,
                const float* __restrict__ W_ih, const float* __restrict__ W_hh,
                const float* __restrict__ b_ih, const float* __restrict__ b_hh,
                const float* __restrict__ W_reg, const float* __restrict__ b_reg,
                const float* __restrict__ W_out, const float* __restrict__ b_out,
                float* __restrict__ ws, float* __restrict__ out)
{
    __shared__ __align__(16) unsigned short Ac[4][2][16 * KROW]; // per-wave A copies, double-buffered (40960 B)
    __shared__ __align__(16) unsigned short stash[BT * ROWEL];   // bf16(m*x), later bf16(x_c)   (26880 B)
    __shared__ unsigned long long mbits[BT * T_];                 // mask bitmaps [r][t]          (3072 B)
    __shared__ float lsum[T_ * 32];                               // per-step per-lane |x-xh|m    (6144 B)
    __shared__ float wout[68];

    const int tid    = threadIdx.x;
    const int lane   = tid & 63;
    const int w      = tid >> 6;      // wave 0..3
    const int g      = lane >> 4;     // k-subgroup / C row-group
    const int cc     = lane & 15;
    const int batch0 = blockIdx.x * BT;
    const int u      = w * 16 + cc;   // this wave's hidden-unit column

    // ---- staging ----
    for (int i = tid; i < 4 * 2 * 16 * KROW / 2; i += 256) ((uint32_t*)Ac)[i] = 0;
    if (tid < 65) wout[tid] = (tid < 64) ? W_out[tid] : b_out[0];

    for (int i = tid; i < BT * (ROWEL / 8); i += 256) {
        const int r = i / (ROWEL / 8);
        const int o = (i - r * (ROWEL / 8)) * 8;
        const float* xp = x_t   + (size_t)(batch0 + r) * ROWEL + o;
        const float* mp = masks + (size_t)(batch0 + r) * ROWEL + o;
        float xv[8], mv[8];
        *(float4*)&xv[0] = *(const float4*)xp;     *(float4*)&xv[4] = *(const float4*)(xp + 4);
        *(float4*)&mv[0] = *(const float4*)mp;     *(float4*)&mv[4] = *(const float4*)(mp + 4);
        unsigned short pk[8];
        #pragma unroll
        for (int k = 0; k < 8; ++k) pk[k] = f2bf_rne(mv[k] * xv[k]);
        *(uint4*)&stash[r * ROWEL + o] = *(const uint4*)pk;
    }
    for (int p = tid; p < BT * T_; p += 256) {
        const int r = p / T_, t = p - r * T_;
        const float* mp = masks + (size_t)(batch0 + r) * ROWEL + t * D_;
        unsigned long long bits = 0;
        for (int d = 0; d < D_; ++d) bits |= (unsigned long long)(mp[d] != 0.0f) << d;
        mbits[p] = bits;
    }

    // ---- weights -> registers ----
    bf16x8 Wf[4][5];                   // gate G for unit u, 5 k-chunks
    #pragma unroll
    for (int G = 0; G < 4; ++G) {
        const int n = G * 64 + u;
        #pragma unroll
        for (int kk = 0; kk < 5; ++kk) {
            bf16x8 v;
            #pragma unroll
            for (int i = 0; i < 8; ++i) {
                const int k = kk * 32 + 8 * g + i;
                float f = 0.f;
                if (k < 70)                  f = W_ih[n * 70 + k];
                else if (k >= 72 && k < 136) f = W_hh[n * 64 + (k - 72)];
                v[i] = (short)f2bf_rne(f);
            }
            Wf[G][kk] = v;
        }
    }
    bf16x8 Wr[3][2];                   // W_reg: 3 n-tiles (cols 0..47, rows>=35 zero)
    #pragma unroll
    for (int nt = 0; nt < 3; ++nt) {
        const int n = nt * 16 + cc;
        #pragma unroll
        for (int kk = 0; kk < 2; ++kk) {
            bf16x8 v;
            #pragma unroll
            for (int i = 0; i < 8; ++i) {
                const int k = kk * 32 + 8 * g + i;
                v[i] = (short)((n < 35) ? f2bf_rne(W_reg[n * 64 + k]) : 0);
            }
            Wr[nt][kk] = v;
        }
    }
    const float brg0 = (cc      < 35) ? b_reg[cc]      : 0.f;
    const float brg1 = (16 + cc < 35) ? b_reg[16 + cc] : 0.f;
    const float brg2 = (32 + cc < 35) ? b_reg[32 + cc] : 0.f;
    // pre-scaled biases: sigm(z+b)=rcp(1+exp2(fma(z,-L2E,bS))), tanh(z+b)=2*rcp(1+exp2(fma(z,-2L2E,bS2)))-1
    const float bIs = -(b_ih[u]       + b_hh[u])       * L2E;
    const float bFs = -(b_ih[64 + u]  + b_hh[64 + u])  * L2E;
    const float bGs = -(b_ih[128 + u] + b_hh[128 + u]) * 2.f * L2E;
    const float bOs = -(b_ih[192 + u] + b_hh[192 + u]) * L2E;
    __syncthreads();

    float c_reg[4] = {0.f, 0.f, 0.f, 0.f};
    uint32_t pxc[12];                  // wave0: previous step's x_c (bf16 bits) for archive
    #pragma unroll
    for (int i = 0; i < 12; ++i) pxc[i] = 0;

    for (int t = 0; t < T_; ++t) {
        unsigned short* Acur = &Ac[w][t & 1][0];

        // archive previous step's x_c into stash (wave0 only; all waves' reads of t-1 done pre-barrier)
        if (w == 0 && g < 2 && t > 0) {
            #pragma unroll
            for (int nt = 0; nt < 3; ++nt) {
                const int col = nt * 16 + cc;
                if (col < 35) {
                    #pragma unroll
                    for (int j = 0; j < 4; ++j)
                        stash[(4 * g + j) * ROWEL + (t - 1) * D_ + col] = (unsigned short)pxc[nt * 4 + j];
                }
            }
        }

        // P1: x_hat = h @ W_reg^T (every wave, redundant)
        bf16x8 ah0 = *(const bf16x8*)&Acur[cc * KROW + 72 + 8 * g];
        bf16x8 ah1 = *(const bf16x8*)&Acur[cc * KROW + 104 + 8 * g];
        f32x4 p0 = {0,0,0,0}, p1 = {0,0,0,0}, p2 = {0,0,0,0};
        p0 = __builtin_amdgcn_mfma_f32_16x16x32_bf16(ah0, Wr[0][0], p0, 0, 0, 0);
        p0 = __builtin_amdgcn_mfma_f32_16x16x32_bf16(ah1, Wr[0][1], p0, 0, 0, 0);
        p1 = __builtin_amdgcn_mfma_f32_16x16x32_bf16(ah0, Wr[1][0], p1, 0, 0, 0);
        p1 = __builtin_amdgcn_mfma_f32_16x16x32_bf16(ah1, Wr[1][1], p1, 0, 0, 0);
        p2 = __builtin_amdgcn_mfma_f32_16x16x32_bf16(ah0, Wr[2][0], p2, 0, 0, 0);
        p2 = __builtin_amdgcn_mfma_f32_16x16x32_bf16(ah1, Wr[2][1], p2, 0, 0, 0);

        // P2 (h-only chunks kk3,kk4 — independent of this step's epilogue)
        bf16x8 a3 = *(const bf16x8*)&Acur[cc * KROW + 96  + 8 * g];
        bf16x8 a4 = *(const bf16x8*)&Acur[cc * KROW + 128 + 8 * g];
        f32x4 gI = {0,0,0,0}, gF = {0,0,0,0}, gG = {0,0,0,0}, gO = {0,0,0,0};
        gI = __builtin_amdgcn_mfma_f32_16x16x32_bf16(a3, Wf[0][3], gI, 0, 0, 0);
        gF = __builtin_amdgcn_mfma_f32_16x16x32_bf16(a3, Wf[1][3], gF, 0, 0, 0);
        gG = __builtin_amdgcn_mfma_f32_16x16x32_bf16(a3, Wf[2][3], gG, 0, 0, 0);
        gO = __builtin_amdgcn_mfma_f32_16x16x32_bf16(a3, Wf[3][3], gO, 0, 0, 0);
        gI = __builtin_amdgcn_mfma_f32_16x16x32_bf16(a4, Wf[0][4], gI, 0, 0, 0);
        gF = __builtin_amdgcn_mfma_f32_16x16x32_bf16(a4, Wf[1][4], gF, 0, 0, 0);
        gG = __builtin_amdgcn_mfma_f32_16x16x32_bf16(a4, Wf[2][4], gG, 0, 0, 0);
        gO = __builtin_amdgcn_mfma_f32_16x16x32_bf16(a4, Wf[3][4], gO, 0, 0, 0);

        // Epilogue: x_c, m -> own A copy; loss partial -> lsum (wave0)
        if (g < 2) {
            float lnum = 0.f;
            unsigned long long mb[4];
            #pragma unroll
            for (int j = 0; j < 4; ++j) mb[j] = mbits[(4 * g + j) * T_ + t];
            #pragma unroll
            for (int nt = 0; nt < 3; ++nt) {
                const int col = nt * 16 + cc;
                const float brg = (nt == 0) ? brg0 : ((nt == 1) ? brg1 : brg2);
                const f32x4 acc = (nt == 0) ? p0 : ((nt == 1) ? p1 : p2);
                if (col < 35) {
                    #pragma unroll
                    for (int j = 0; j < 4; ++j) {
                        const int row = 4 * g + j;
                        const float xh = acc[j] + brg;
                        const unsigned short xm16 = stash[row * ROWEL + t * D_ + col];
                        const float xm = bf2f(xm16);
                        const bool m = (mb[j] >> col) & 1;
                        lnum += m ? fabsf(xm - xh) : 0.f;
                        const uint32_t xcb = m ? (uint32_t)xm16 : (fbits(xh) >> 16);
                        Acur[row * KROW + col]      = (unsigned short)xcb;
                        Acur[row * KROW + 35 + col] = m ? (unsigned short)0x3F80 : (unsigned short)0;
                        if (w == 0) pxc[nt * 4 + j] = xcb;
                    }
                }
            }
            if (w == 0) lsum[t * 32 + lane] = lnum;
        }

        // P2 rest (kk0..2 — after own epilogue writes, same-wave lgkm ordering)
        bf16x8 a0 = *(const bf16x8*)&Acur[cc * KROW + 0  + 8 * g];
        bf16x8 a1 = *(const bf16x8*)&Acur[cc * KROW + 32 + 8 * g];
        bf16x8 a2 = *(const bf16x8*)&Acur[cc * KROW + 64 + 8 * g];
        gI = __builtin_amdgcn_mfma_f32_16x16x32_bf16(a0, Wf[0][0], gI, 0, 0, 0);
        gF = __builtin_amdgcn_mfma_f32_16x16x32_bf16(a0, Wf[1][0], gF, 0, 0, 0);
        gG = __builtin_amdgcn_mfma_f32_16x16x32_bf16(a0, Wf[2][0], gG, 0, 0, 0);
        gO = __builtin_amdgcn_mfma_f32_16x16x32_bf16(a0, Wf[3][0], gO, 0, 0, 0);
        gI = __builtin_amdgcn_mfma_f32_16x16x32_bf16(a1, Wf[0][1], gI, 0, 0, 0);
        gF = __builtin_amdgcn_mfma_f32_16x16x32_bf16(a1, Wf[1][1], gF, 0, 0, 0);
        gG = __builtin_amdgcn_mfma_f32_16x16x32_bf16(a1, Wf[2][1], gG, 0, 0, 0);
        gO = __builtin_amdgcn_mfma_f32_16x16x32_bf16(a1, Wf[3][1], gO, 0, 0, 0);
        gI = __builtin_amdgcn_mfma_f32_16x16x32_bf16(a2, Wf[0][2], gI, 0, 0, 0);
        gF = __builtin_amdgcn_mfma_f32_16x16x32_bf16(a2, Wf[1][2], gF, 0, 0, 0);
        gG = __builtin_amdgcn_mfma_f32_16x16x32_bf16(a2, Wf[2][2], gG, 0, 0, 0);
        gO = __builtin_amdgcn_mfma_f32_16x16x32_bf16(a2, Wf[3][2], gO, 0, 0, 0);

        // P3: cell update (rcp/exp2-based), broadcast h to all 4 copies' next buffer
        if (g < 2) {
            unsigned short* An0 = &Ac[0][(t + 1) & 1][0];
            unsigned short* An1 = &Ac[1][(t + 1) & 1][0];
            unsigned short* An2 = &Ac[2][(t + 1) & 1][0];
            unsigned short* An3 = &Ac[3][(t + 1) & 1][0];
            #pragma unroll
            for (int j = 0; j < 4; ++j) {
                const float iv = rcp_(1.f + exp2_(fmaf(gI[j], -L2E,       bIs)));
                const float fv = rcp_(1.f + exp2_(fmaf(gF[j], -L2E,       bFs)));
                const float gv = fmaf(2.f, rcp_(1.f + exp2_(fmaf(gG[j], -2.f * L2E, bGs))), -1.f);
                const float ov = rcp_(1.f + exp2_(fmaf(gO[j], -L2E,       bOs)));
                const float cn = fmaf(fv, c_reg[j], iv * gv);
                c_reg[j] = cn;
                const float th = fmaf(2.f, rcp_(1.f + exp2_(cn * (-2.f * L2E))), -1.f);
                const unsigned short h16 = (unsigned short)(fbits(ov * th) >> 16);
                const int ha = (4 * g + j) * KROW + 72 + u;
                An0[ha] = h16; An1[ha] = h16; An2[ha] = h16; An3[ha] = h16;
            }
        }
        __syncthreads();   // the single per-step barrier: h visible to all waves
    }

    // ---- archive final step's x_c ----
    if (w == 0 && g < 2) {
        #pragma unroll
        for (int nt = 0; nt < 3; ++nt) {
            const int col = nt * 16 + cc;
            if (col < 35) {
                #pragma unroll
                for (int j = 0; j < 4; ++j)
                    stash[(4 * g + j) * ROWEL + (T_ - 1) * D_ + col] = (unsigned short)pxc[nt * 4 + j];
            }
        }
    }
    __syncthreads();

    // ---- y_h (wave0): final h lives in Ac[0][0] rows 0..7 ----
    if (w == 0 && cc < BT) {
        float p = 0.f;
        #pragma unroll
        for (int k = 0; k < 16; ++k)
            p += bf2f(Ac[0][0][cc * KROW + 72 + 16 * g + k]) * wout[16 * g + k];
        p += __shfl_xor(p, 16, 64);
        p += __shfl_xor(p, 32, 64);
        if (lane < 16) out[1 + batch0 + cc] = rcp_(1.f + exp2_(-(p + wout[64]) * L2E));
    }

    // ---- loss partials: waves split t; one pair of spread atomics per t ----
    {
        #pragma unroll 1
        for (int tt = 0; tt < 12; ++tt) {
            const int t = w * 12 + tt;
            float v = (lane < 32) ? lsum[t * 32 + lane] : 0.f;
            v += __shfl_xor(v, 1, 64);  v += __shfl_xor(v, 2, 64);
            v += __shfl_xor(v, 4, 64);  v += __shfl_xor(v, 8, 64);
            v += __shfl_xor(v, 16, 64);
            float den = (lane < BT) ? (float)__popcll(mbits[lane * T_ + t]) : 0.f;
            den += __shfl_xor(den, 1, 64); den += __shfl_xor(den, 2, 64);
            den += __shfl_xor(den, 4, 64);
            if (lane == 0) {
                atomicAdd(&ws[t * 8 + (blockIdx.x & 7)], v);
                atomicAdd(&ws[(T_ + t) * 8 + (blockIdx.x & 7)], den);
            }
        }
    }

    // ---- bulk dump imputations (bf16 x_c archived in stash) ----
    for (int r = 0; r < BT; ++r) {
        float* op = out + 1 + B_ + (size_t)(batch0 + r) * ROWEL;
        for (int o = tid; o < ROWEL; o += 256) op[o] = bf2f(stash[r * ROWEL + o]);
    }
}

// loss = (1/T) * sum_t num[t] / (den[t] + 1e-5); slots spread 8-way
__global__ void post_kernel(const float* __restrict__ ws, float* __restrict__ out)
{
    const int t = threadIdx.x;  // 64 threads
    float v = 0.f;
    if (t < T_) {
        float num = 0.f, den = 0.f;
        #pragma unroll
        for (int s = 0; s < 8; ++s) {
            num += ws[t * 8 + s];
            den += ws[(T_ + t) * 8 + s];
        }
        v = num / (den + 1e-5f);
    }
    #pragma unroll
    for (int off = 1; off < 64; off <<= 1) v += __shfl_xor(v, off, 64);
    if (t == 0) out[0] = v * (1.0f / T_);
}

extern "C" void kernel_launch(void* const* d_in, const int* in_sizes, int n_in,
                              void* d_out, int out_size, void* d_ws, size_t ws_size,
                              hipStream_t stream) {
    const float* x_t   = (const float*)d_in[0];
    const float* masks = (const float*)d_in[1];
    const float* W_ih  = (const float*)d_in[6];
    const float* W_hh  = (const float*)d_in[7];
    const float* b_ih  = (const float*)d_in[8];
    const float* b_hh  = (const float*)d_in[9];
    const float* W_reg = (const float*)d_in[10];
    const float* b_reg = (const float*)d_in[11];
    const float* W_out = (const float*)d_in[14];
    const float* b_out = (const float*)d_in[15];
    float* out = (float*)d_out;
    float* ws  = (float*)d_ws;

    hipMemsetAsync(ws, 0, 2 * T_ * 8 * sizeof(float), stream);
    brits_main<<<B_ / BT, 256, 0, stream>>>(x_t, masks, W_ih, W_hh, b_ih, b_hh,
                                            W_reg, b_reg, W_out, b_out, ws, out);
    post_kernel<<<1, 64, 0, stream>>>(ws, out);
}

// Round 6
// 87.553 us; speedup vs baseline: 1.6747x; 1.6747x over previous
//
#include <hip/hip_runtime.h>
#include <stdint.h>

#define B_    4096
#define T_    48
#define D_    35
#define KROW  168           // A-row stride (elems); MFMA reads k 0..159; 136..167 zero
#define BT    16            // batch rows per block (all real -> no duplicated MFMA work)
#define ROWEL (T_ * D_)     // 1680
#define L2E   1.44269504f

typedef float f32x4 __attribute__((ext_vector_type(4)));
typedef short bf16x8 __attribute__((ext_vector_type(8)));

__device__ __forceinline__ uint32_t fbits(float x) { union { float f; uint32_t u; } v; v.f = x; return v.u; }
__device__ __forceinline__ float bitsf(uint32_t u) { union { uint32_t u; float f; } v; v.u = u; return v.f; }
__device__ __forceinline__ float bf2f(unsigned short b) { return bitsf(((uint32_t)b) << 16); }
__device__ __forceinline__ unsigned short f2bf_rne(float x) {
    uint32_t u = fbits(x);
    return (unsigned short)((u + 0x7fffu + ((u >> 16) & 1u)) >> 16);
}
__device__ __forceinline__ float rcp_(float x)  { return __builtin_amdgcn_rcpf(x); }
__device__ __forceinline__ float exp2_(float x) { return __builtin_amdgcn_exp2f(x); }

// K-axis layout (A tile and weight fragments):
//   k 0..34 = x_c -> W_ih[:,0:35] ; k 35..69 = m -> W_ih[:,35:70]
//   k 70..71 = 0  ; k 72..135 = h -> W_hh   ; k 136..159 = 0
// Chunk schedule: kk2(64..95: m-tail+h), kk3, kk4 and P1 issue PRE-bar1
// (m pre-written one step ahead); kk0, kk1 (x_c-dependent) issue POST-bar1.

__global__ __launch_bounds__(256, 1)
void brits_main(const float* __restrict__ x_t, const float* __restrict__ masks,
                const float* __restrict__ W_ih, const float* __restrict__ W_hh,
                const float* __restrict__ b_ih, const float* __restrict__ b_hh,
                const float* __restrict__ W_reg, const float* __restrict__ b_reg,
                const float* __restrict__ W_out, const float* __restrict__ b_out,
                float* __restrict__ ws, float* __restrict__ out)
{
    __shared__ __align__(16) unsigned short Abuf[2][BT * KROW];   // 10752 B
    __shared__ __align__(16) unsigned short stash[BT * ROWEL];    // 53760 B: bf16(m*x) -> bf16(x_c)
    __shared__ unsigned long long mbits[BT * T_];                 // 6144 B
    __shared__ float lsum[T_ * 3 * 64];                           // 36864 B
    __shared__ float wout[65];

    const int tid    = threadIdx.x;
    const int lane   = tid & 63;
    const int w      = tid >> 6;      // wave 0..3
    const int g      = lane >> 4;     // k-subgroup / C row-group
    const int cc     = lane & 15;
    const int batch0 = blockIdx.x * BT;
    const int u      = w * 16 + cc;   // gate unit (all waves) / x_hat col (w<3)

    // ---- staging ----
    for (int i = tid; i < BT * KROW; i += 256) ((uint32_t*)Abuf)[i] = 0;  // both buffers
    if (tid < 65) wout[tid] = (tid < 64) ? W_out[tid] : b_out[0];

    for (int i = tid; i < BT * (ROWEL / 8); i += 256) {
        const int r = i / 210;
        const int o = (i - r * 210) * 8;
        const float* xp = x_t   + (size_t)(batch0 + r) * ROWEL + o;
        const float* mp = masks + (size_t)(batch0 + r) * ROWEL + o;
        float xv[8], mv[8];
        *(float4*)&xv[0] = *(const float4*)xp; *(float4*)&xv[4] = *(const float4*)(xp + 4);
        *(float4*)&mv[0] = *(const float4*)mp; *(float4*)&mv[4] = *(const float4*)(mp + 4);
        unsigned short pk[8];
        #pragma unroll
        for (int k = 0; k < 8; ++k) pk[k] = f2bf_rne(mv[k] * xv[k]);
        *(uint4*)&stash[r * ROWEL + o] = *(const uint4*)pk;
    }
    for (int p = tid; p < BT * T_; p += 256) {
        const int r = p / T_, t = p - r * T_;
        const float* mp = masks + (size_t)(batch0 + r) * ROWEL + t * D_;
        unsigned long long bits = 0;
        for (int d = 0; d < D_; ++d) bits |= (unsigned long long)(mp[d] != 0.0f) << d;
        mbits[p] = bits;
    }

    // ---- weights -> registers ----
    bf16x8 Wf[4][5];
    #pragma unroll
    for (int G = 0; G < 4; ++G) {
        const int n = G * 64 + u;
        #pragma unroll
        for (int kk = 0; kk < 5; ++kk) {
            bf16x8 v;
            #pragma unroll
            for (int i = 0; i < 8; ++i) {
                const int k = kk * 32 + 8 * g + i;
                float f = 0.f;
                if (k < 70)                  f = W_ih[n * 70 + k];
                else if (k >= 72 && k < 136) f = W_hh[n * 64 + (k - 72)];
                v[i] = (short)f2bf_rne(f);
            }
            Wf[G][kk] = v;
        }
    }
    bf16x8 Wr0, Wr1;   // x_hat weights for col u (w<3)
    {
        const bool ok = (w < 3) && (u < 35);
        #pragma unroll
        for (int i = 0; i < 8; ++i) {
            Wr0[i] = (short)(ok ? f2bf_rne(W_reg[u * 64 + 8 * g + i])      : 0);
            Wr1[i] = (short)(ok ? f2bf_rne(W_reg[u * 64 + 32 + 8 * g + i]) : 0);
        }
    }
    const float brg = ((w < 3) && (u < 35)) ? b_reg[u] : 0.f;
    const float bIs = -(b_ih[u]       + b_hh[u])       * L2E;
    const float bFs = -(b_ih[64 + u]  + b_hh[64 + u])  * L2E;
    const float bGs = -(b_ih[128 + u] + b_hh[128 + u]) * 2.f * L2E;
    const float bOs = -(b_ih[192 + u] + b_hh[192 + u]) * L2E;
    __syncthreads();   // stash + mbits ready

    // ---- per-lane mask bitmaps over t, first x*m prefetch, m(0) pre-write ----
    const bool pl = (w < 3) && (u < 35);
    unsigned long long PM[4] = {0, 0, 0, 0};
    uint32_t xmr[4] = {0, 0, 0, 0};
    if (pl) {
        #pragma unroll
        for (int j = 0; j < 4; ++j) {
            const int row = 4 * g + j;
            unsigned long long pm = 0;
            for (int t = 0; t < T_; ++t)
                pm |= ((mbits[row * T_ + t] >> u) & 1ull) << t;
            PM[j] = pm;
            xmr[j] = stash[row * ROWEL + u];                       // t=0
            Abuf[0][row * KROW + 35 + u] = (pm & 1ull) ? (unsigned short)0x3F80 : (unsigned short)0;
        }
    }
    __syncthreads();   // m(0) visible

    float c_reg[4] = {0.f, 0.f, 0.f, 0.f};

    for (int t = 0; t < T_; ++t) {
        unsigned short* A  = Abuf[t & 1];
        unsigned short* An = Abuf[(t + 1) & 1];

        // ---- pre-bar1: everything that depends only on h(t-1) and m(t) ----
        bf16x8 ah0 = *(const bf16x8*)&A[cc * KROW + 72  + 8 * g];
        bf16x8 ah1 = *(const bf16x8*)&A[cc * KROW + 104 + 8 * g];
        bf16x8 a2  = *(const bf16x8*)&A[cc * KROW + 64  + 8 * g];
        bf16x8 a3  = *(const bf16x8*)&A[cc * KROW + 96  + 8 * g];
        bf16x8 a4  = *(const bf16x8*)&A[cc * KROW + 128 + 8 * g];

        f32x4 gI = {0,0,0,0}, gF = {0,0,0,0}, gG = {0,0,0,0}, gO = {0,0,0,0};
        gI = __builtin_amdgcn_mfma_f32_16x16x32_bf16(a2, Wf[0][2], gI, 0, 0, 0);
        gF = __builtin_amdgcn_mfma_f32_16x16x32_bf16(a2, Wf[1][2], gF, 0, 0, 0);
        gG = __builtin_amdgcn_mfma_f32_16x16x32_bf16(a2, Wf[2][2], gG, 0, 0, 0);
        gO = __builtin_amdgcn_mfma_f32_16x16x32_bf16(a2, Wf[3][2], gO, 0, 0, 0);
        gI = __builtin_amdgcn_mfma_f32_16x16x32_bf16(a3, Wf[0][3], gI, 0, 0, 0);
        gF = __builtin_amdgcn_mfma_f32_16x16x32_bf16(a3, Wf[1][3], gF, 0, 0, 0);
        gG = __builtin_amdgcn_mfma_f32_16x16x32_bf16(a3, Wf[2][3], gG, 0, 0, 0);
        gO = __builtin_amdgcn_mfma_f32_16x16x32_bf16(a3, Wf[3][3], gO, 0, 0, 0);
        gI = __builtin_amdgcn_mfma_f32_16x16x32_bf16(a4, Wf[0][4], gI, 0, 0, 0);
        gF = __builtin_amdgcn_mfma_f32_16x16x32_bf16(a4, Wf[1][4], gF, 0, 0, 0);
        gG = __builtin_amdgcn_mfma_f32_16x16x32_bf16(a4, Wf[2][4], gG, 0, 0, 0);
        gO = __builtin_amdgcn_mfma_f32_16x16x32_bf16(a4, Wf[3][4], gO, 0, 0, 0);

        if (w < 3) {
            f32x4 p0 = {0,0,0,0};
            p0 = __builtin_amdgcn_mfma_f32_16x16x32_bf16(ah0, Wr0, p0, 0, 0, 0);
            p0 = __builtin_amdgcn_mfma_f32_16x16x32_bf16(ah1, Wr1, p0, 0, 0, 0);
            float lnum = 0.f;
            if (u < 35) {
                #pragma unroll
                for (int j = 0; j < 4; ++j) {
                    const int row = 4 * g + j;
                    const float xh = p0[j] + brg;
                    const float xm = bf2f((unsigned short)xmr[j]);
                    const uint32_t mb = (uint32_t)(PM[j] >> t) & 1u;
                    lnum += mb ? fabsf(xm - xh) : 0.f;
                    const unsigned short xc16 = mb ? (unsigned short)xmr[j] : f2bf_rne(xh);
                    A[row * KROW + u] = xc16;                               // x_c(t)
                    An[row * KROW + 35 + u] =                               // m(t+1), one step ahead
                        ((PM[j] >> (t + 1)) & 1ull) ? (unsigned short)0x3F80 : (unsigned short)0;
                    stash[row * ROWEL + t * D_ + u] = xc16;                 // imputation archive
                }
            }
            lsum[(t * 3 + w) * 64 + lane] = lnum;
        }
        __syncthreads();   // bar1 (lgkm only): x_c visible

        // ---- post-bar1: x_c-dependent chunks, prefetch, cell update ----
        bf16x8 a0 = *(const bf16x8*)&A[cc * KROW + 0  + 8 * g];
        bf16x8 a1 = *(const bf16x8*)&A[cc * KROW + 32 + 8 * g];
        gI = __builtin_amdgcn_mfma_f32_16x16x32_bf16(a0, Wf[0][0], gI, 0, 0, 0);
        gF = __builtin_amdgcn_mfma_f32_16x16x32_bf16(a0, Wf[1][0], gF, 0, 0, 0);
        gG = __builtin_amdgcn_mfma_f32_16x16x32_bf16(a0, Wf[2][0], gG, 0, 0, 0);
        gO = __builtin_amdgcn_mfma_f32_16x16x32_bf16(a0, Wf[3][0], gO, 0, 0, 0);
        gI = __builtin_amdgcn_mfma_f32_16x16x32_bf16(a1, Wf[0][1], gI, 0, 0, 0);
        gF = __builtin_amdgcn_mfma_f32_16x16x32_bf16(a1, Wf[1][1], gF, 0, 0, 0);
        gG = __builtin_amdgcn_mfma_f32_16x16x32_bf16(a1, Wf[2][1], gG, 0, 0, 0);
        gO = __builtin_amdgcn_mfma_f32_16x16x32_bf16(a1, Wf[3][1], gO, 0, 0, 0);

        if (pl && t + 1 < T_) {          // prefetch next step's m*x (off critical path)
            #pragma unroll
            for (int j = 0; j < 4; ++j)
                xmr[j] = stash[(4 * g + j) * ROWEL + (t + 1) * D_ + u];
        }

        #pragma unroll
        for (int j = 0; j < 4; ++j) {
            const float iv = rcp_(1.f + exp2_(fmaf(gI[j], -L2E,       bIs)));
            const float fv = rcp_(1.f + exp2_(fmaf(gF[j], -L2E,       bFs)));
            const float gv = fmaf(2.f, rcp_(1.f + exp2_(fmaf(gG[j], -2.f * L2E, bGs))), -1.f);
            const float ov = rcp_(1.f + exp2_(fmaf(gO[j], -L2E,       bOs)));
            const float cn = fmaf(fv, c_reg[j], iv * gv);
            c_reg[j] = cn;
            const float th = fmaf(2.f, rcp_(1.f + exp2_(cn * (-2.f * L2E))), -1.f);
            An[(4 * g + j) * KROW + 72 + u] = (unsigned short)(fbits(ov * th) >> 16);
        }
        __syncthreads();   // bar2 (lgkm only): h(t) visible
    }

    // ---- loss partials: per-t reduce in LDS, spread atomics once per block ----
    if (tid < T_) {
        const int t = tid;
        float num = 0.f;
        for (int i = 0; i < 192; ++i) num += lsum[t * 192 + i];
        float den = 0.f;
        for (int r = 0; r < BT; ++r) den += (float)__popcll(mbits[r * T_ + t]);
        atomicAdd(&ws[t * 8 + (blockIdx.x & 7)], num);
        atomicAdd(&ws[(T_ + t) * 8 + (blockIdx.x & 7)], den);
    }

    // ---- y_h = sigmoid(h_final @ W_out^T + b_out); h(T-1) in Abuf[0] ----
    if (w == 1) {
        float p = 0.f;
        #pragma unroll
        for (int k = 0; k < 16; ++k)
            p += bf2f(Abuf[0][cc * KROW + 72 + 16 * g + k]) * wout[16 * g + k];
        p += __shfl_xor(p, 16, 64);
        p += __shfl_xor(p, 32, 64);
        if (lane < 16) out[1 + batch0 + cc] = rcp_(1.f + exp2_(-(p + wout[64]) * L2E));
    }

    // ---- bulk dump imputations ----
    for (int i = tid; i < BT * ROWEL; i += 256) {
        const int r = i / ROWEL;
        const int o = i - r * ROWEL;
        out[1 + B_ + (size_t)(batch0 + r) * ROWEL + o] = bf2f(stash[i]);
    }
}

// loss = (1/T) * sum_t num[t] / (den[t] + 1e-5); slots spread 8-way
__global__ void post_kernel(const float* __restrict__ ws, float* __restrict__ out)
{
    const int t = threadIdx.x;  // 64 threads
    float v = 0.f;
    if (t < T_) {
        float num = 0.f, den = 0.f;
        #pragma unroll
        for (int s = 0; s < 8; ++s) {
            num += ws[t * 8 + s];
            den += ws[(T_ + t) * 8 + s];
        }
        v = num / (den + 1e-5f);
    }
    #pragma unroll
    for (int off = 1; off < 64; off <<= 1) v += __shfl_xor(v, off, 64);
    if (t == 0) out[0] = v * (1.0f / T_);
}

extern "C" void kernel_launch(void* const* d_in, const int* in_sizes, int n_in,
                              void* d_out, int out_size, void* d_ws, size_t ws_size,
                              hipStream_t stream) {
    const float* x_t   = (const float*)d_in[0];
    const float* masks = (const float*)d_in[1];
    const float* W_ih  = (const float*)d_in[6];
    const float* W_hh  = (const float*)d_in[7];
    const float* b_ih  = (const float*)d_in[8];
    const float* b_hh  = (const float*)d_in[9];
    const float* W_reg = (const float*)d_in[10];
    const float* b_reg = (const float*)d_in[11];
    const float* W_out = (const float*)d_in[14];
    const float* b_out = (const float*)d_in[15];
    float* out = (float*)d_out;
    float* ws  = (float*)d_ws;

    hipMemsetAsync(ws, 0, 2 * T_ * 8 * sizeof(float), stream);
    brits_main<<<B_ / BT, 256, 0, stream>>>(x_t, masks, W_ih, W_hh, b_ih, b_hh,
                                            W_reg, b_reg, W_out, b_out, ws, out);
    post_kernel<<<1, 64, 0, stream>>>(ws, out);
}